// Round 2
// baseline (297.249 us; speedup 1.0000x reference)
//
#include <hip/hip_runtime.h>
#include <cstddef>

// Problem constants
#define B_TOT   256
#define IN_CAPS 1152
#define KDIM    8
#define NJ      10
#define ND      16
#define JD      160           // NJ*ND

// Tiling
#define BB      4             // batches per block (W register reuse factor)
#define ISPLIT  8             // grid = (256/BB)*ISPLIT = 512 blocks -> 2 blocks/CU
#define IRANGE  (IN_CAPS/ISPLIT)   // 144
#define CI      16            // i per chunk == IPAR (1 i per thread-group)
#define IPAR    16
#define NTHREADS 640          // IPAR * NJ * 4 (d-quads); == BB*JD for the tail
#define NCHUNK  (IRANGE/CI)        // 9
#define WSTRIDE (NJ*KDIM*ND)       // 1280 floats per i
#define LPAD    12            // logit row padded 10 -> 12 floats (16B-aligned rows)
#define EPSQ    1e-7f

__device__ __forceinline__ float dot4(float4 a, float4 b) {
    return a.x*b.x + a.y*b.y + a.z*b.z + a.w*b.w;
}

// One routing iteration: s_out[b,j,d] += sum_i c[b,i,j] * u_hat[b,i,j,d]
// u_hat recomputed on the fly from x (LDS, staged once) and W (L2-resident per XCD).
// ITER==1: c uniform = 0.1 (softmax of zeros), applied as premul at the end.
// ITER==2: logits = u_hat . v1,       v1 = squash(s1)   (squash fused in head)
// ITER==3: logits = u_hat . (v1+v2)   (linearity of the b-update in v)
template<int ITER>
__global__ __launch_bounds__(NTHREADS, 5)   // 5 waves/EU -> 2 blocks/CU, VGPR cap ~96
void iter_kernel(const float* __restrict__ x, const float* __restrict__ Wt,
                 const float* __restrict__ s1, const float* __restrict__ s2,
                 float* __restrict__ s_out)
{
    const int g   = blockIdx.x >> 3;       // b-group 0..63
    const int isp = blockIdx.x & 7;        // i-split == XCD id (round-robin dispatch)
    const int b0  = g * BB;
    const int i_begin = isp * IRANGE;

    const int t = threadIdx.x;
    const int i_par = t / 40;              // 0..15
    const int r  = t - i_par * 40;
    const int j  = r >> 2;                 // 0..9
    const int dq = r & 3;                  // 0..3  (owns d = dq*4..dq*4+3)

    __shared__ float x_lds[BB][IRANGE][KDIM];      // 18.0 KB (whole slice, staged once)
    __shared__ float logit_lds[2][BB][CI][LPAD];   // 6.0 KB (parity double-buffered)
    __shared__ float s_lds[BB][JD];                // 2.5 KB

    // head: v for this thread's (j, dq) — fused squash of previous iteration(s)
    float4 vs[BB];
    if (ITER >= 2) {
        #pragma unroll
        for (int bb = 0; bb < BB; ++bb) {
            const float4 a = *(const float4*)(s1 + (size_t)(b0 + bb) * JD + j * ND + dq * 4);
            float q2 = dot4(a, a);
            q2 += __shfl_xor(q2, 1);           // sum over the 4-lane d-quad (16 d total)
            q2 += __shfl_xor(q2, 2);
            const float sc = q2 / (1.f + q2) / sqrtf(q2 + EPSQ);
            vs[bb] = make_float4(a.x * sc, a.y * sc, a.z * sc, a.w * sc);
            if (ITER == 3) {
                const float4 bv = *(const float4*)(s2 + (size_t)(b0 + bb) * JD + j * ND + dq * 4);
                float r2 = dot4(bv, bv);
                r2 += __shfl_xor(r2, 1);
                r2 += __shfl_xor(r2, 2);
                const float sc2 = r2 / (1.f + r2) / sqrtf(r2 + EPSQ);
                vs[bb].x += bv.x * sc2; vs[bb].y += bv.y * sc2;
                vs[bb].z += bv.z * sc2; vs[bb].w += bv.w * sc2;
            }
        }
    }

    // stage entire x slice: BB * 288 float4, contiguous & coalesced (2 rounds)
    {
        const int NF = (IRANGE * KDIM) / 4;    // 288 float4 per batch
        for (int idx = t; idx < BB * NF; idx += NTHREADS) {
            const int bb = idx / NF;
            const int f  = idx - bb * NF;
            ((float4*)&x_lds[bb][0][0])[f] =
                ((const float4*)(x + (size_t)(b0 + bb) * IN_CAPS * KDIM
                                   + (size_t)i_begin * KDIM))[f];
        }
    }
    __syncthreads();

    float4 s_acc[BB];
    #pragma unroll
    for (int bb = 0; bb < BB; ++bb) s_acc[bb] = make_float4(0.f, 0.f, 0.f, 0.f);

    const float* wp = Wt + (size_t)((i_begin + i_par) * NJ + j) * (KDIM * ND) + dq * 4;

    for (int c = 0; c < NCHUNK; ++c) {
        const int il = c * CI + i_par;
        const int p  = c & 1;

        // u_hat fragments in registers; W streamed one float4 at a time (low VGPR)
        float4 u[BB];
        #pragma unroll
        for (int bb = 0; bb < BB; ++bb) u[bb] = make_float4(0.f, 0.f, 0.f, 0.f);
        #pragma unroll
        for (int h = 0; h < 2; ++h) {
            float xs[BB][4];
            #pragma unroll
            for (int bb = 0; bb < BB; ++bb) {
                const float4 xv = *(const float4*)&x_lds[bb][il][h * 4];  // ds_read_b128
                xs[bb][0] = xv.x; xs[bb][1] = xv.y; xs[bb][2] = xv.z; xs[bb][3] = xv.w;
            }
            #pragma unroll
            for (int kk = 0; kk < 4; ++kk) {
                const float4 w4 = *(const float4*)(wp + (h * 4 + kk) * ND);
                #pragma unroll
                for (int bb = 0; bb < BB; ++bb) {
                    const float xv = xs[bb][kk];
                    u[bb].x += xv * w4.x; u[bb].y += xv * w4.y;
                    u[bb].z += xv * w4.z; u[bb].w += xv * w4.w;
                }
            }
        }

        if (ITER == 1) {
            // uniform c: just accumulate. NO barriers in this loop at all.
            #pragma unroll
            for (int bb = 0; bb < BB; ++bb) {
                s_acc[bb].x += u[bb].x; s_acc[bb].y += u[bb].y;
                s_acc[bb].z += u[bb].z; s_acc[bb].w += u[bb].w;
            }
        } else {
            // logits: after the quad shfl, EVERY thread holds its own logit
            float lg[BB];
            #pragma unroll
            for (int bb = 0; bb < BB; ++bb) {
                float v = dot4(u[bb], vs[bb]);
                v += __shfl_xor(v, 1);         // reduce over the 4-lane d-quad group
                v += __shfl_xor(v, 2);
                lg[bb] = v;
                if (dq == 0) logit_lds[p][bb][i_par][j] = v;
            }
            __syncthreads();                   // the ONLY barrier per chunk

            // per-thread softmax from the padded logit row (no c_lds round-trip;
            // double-buffered logits make next chunk's writes race-free)
            #pragma unroll
            for (int bb = 0; bb < BB; ++bb) {
                const float* row = &logit_lds[p][bb][i_par][0];
                const float4 r0 = *(const float4*)(row);
                const float4 r1 = *(const float4*)(row + 4);
                const float2 r2 = *(const float2*)(row + 8);
                const float m = fmaxf(fmaxf(fmaxf(r0.x, r0.y), fmaxf(r0.z, r0.w)),
                               fmaxf(fmaxf(fmaxf(r1.x, r1.y), fmaxf(r1.z, r1.w)),
                                     fmaxf(r2.x, r2.y)));
                const float ssum =
                    __expf(r0.x - m) + __expf(r0.y - m) + __expf(r0.z - m) + __expf(r0.w - m) +
                    __expf(r1.x - m) + __expf(r1.y - m) + __expf(r1.z - m) + __expf(r1.w - m) +
                    __expf(r2.x - m) + __expf(r2.y - m);
                const float cc = __fdividef(__expf(lg[bb] - m), ssum);
                s_acc[bb].x += cc * u[bb].x; s_acc[bb].y += cc * u[bb].y;
                s_acc[bb].z += cc * u[bb].z; s_acc[bb].w += cc * u[bb].w;
            }
        }

        wp += (size_t)CI * WSTRIDE;
    }

    // block-level reduction over i_par groups via LDS, then one global atomic each
    ((float*)s_lds)[t] = 0.f;   // NTHREADS == BB*JD
    __syncthreads();
    const float premul = (ITER == 1) ? 0.1f : 1.0f;   // softmax(zeros) over 10 caps
    #pragma unroll
    for (int bb = 0; bb < BB; ++bb) {
        atomicAdd(&s_lds[bb][j * ND + dq * 4 + 0], s_acc[bb].x * premul);
        atomicAdd(&s_lds[bb][j * ND + dq * 4 + 1], s_acc[bb].y * premul);
        atomicAdd(&s_lds[bb][j * ND + dq * 4 + 2], s_acc[bb].z * premul);
        atomicAdd(&s_lds[bb][j * ND + dq * 4 + 3], s_acc[bb].w * premul);
    }
    __syncthreads();
    {
        const int bb = t / JD;
        const int jd = t - bb * JD;
        unsafeAtomicAdd(&s_out[(size_t)(b0 + bb) * JD + jd], s_lds[bb][jd]);
    }
}

// final squash per (b,j): v = s * s2/(1+s2)/sqrt(s2+eps); 16-lane shuffle reduction.
__global__ __launch_bounds__(256)
void squash_kernel(const float* __restrict__ s, float* __restrict__ out)
{
    const int idx = blockIdx.x * 256 + threadIdx.x;   // grid 160 -> exactly 40960
    const float sv = s[idx];
    float sq = sv * sv;
    sq += __shfl_xor(sq, 1);
    sq += __shfl_xor(sq, 2);
    sq += __shfl_xor(sq, 4);
    sq += __shfl_xor(sq, 8);    // sum over the 16 d-lanes (16-aligned in wave)
    const float scale = sq / (1.0f + sq) / sqrtf(sq + EPSQ);
    out[idx] = sv * scale;
}

extern "C" void kernel_launch(void* const* d_in, const int* in_sizes, int n_in,
                              void* d_out, int out_size, void* d_ws, size_t ws_size,
                              hipStream_t stream)
{
    const float* x  = (const float*)d_in[0];   // [256,1152,8]
    const float* Wt = (const float*)d_in[1];   // [1152,10,8,16]
    float* out = (float*)d_out;                // [256,10,16]
    float* s1  = (float*)d_ws;                 // 40960 floats each
    float* s2  = s1 + (size_t)B_TOT * JD;
    float* s3  = s2 + (size_t)B_TOT * JD;

    // ws is re-poisoned before every launch: zero the three s accumulators (480 KB)
    hipMemsetAsync(d_ws, 0, 3 * (size_t)B_TOT * JD * sizeof(float), stream);

    dim3 grid((B_TOT / BB) * ISPLIT), blk(NTHREADS);

    iter_kernel<1><<<grid, blk, 0, stream>>>(x, Wt, nullptr, nullptr, s1);  // s1 = sum(0.1*u)
    iter_kernel<2><<<grid, blk, 0, stream>>>(x, Wt, s1, nullptr, s2);       // v1 in-head
    iter_kernel<3><<<grid, blk, 0, stream>>>(x, Wt, s1, s2, s3);            // v1+v2 in-head
    squash_kernel<<<dim3((B_TOT * JD) / 256), dim3(256), 0, stream>>>(s3, out);
}

// Round 3
// 237.766 us; speedup vs baseline: 1.2502x; 1.2502x over previous
//
#include <hip/hip_runtime.h>
#include <cstddef>

// Problem constants
#define B_TOT   256
#define IN_CAPS 1152
#define KDIM    8
#define NJ      10
#define ND      16
#define JD      160           // NJ*ND

// Tiling
#define BB      4             // batches per block (W register reuse factor)
#define ISPLIT  8             // grid = (256/BB)*ISPLIT = 512 blocks -> 2 blocks/CU
#define IRANGE  (IN_CAPS/ISPLIT)   // 144
#define CI      16            // i per chunk == IPAR (1 i per thread-group)
#define IPAR    16
#define NTHREADS 640          // IPAR * NJ * 4 (d-quads); == BB*JD == BB*CI*NJ
#define NCHUNK  (IRANGE/CI)        // 9
#define WSTRIDE (NJ*KDIM*ND)       // 1280 floats per i
#define EPSQ    1e-7f

__device__ __forceinline__ float dot4(float4 a, float4 b) {
    return a.x*b.x + a.y*b.y + a.z*b.z + a.w*b.w;
}

// One routing iteration: s_out[b,j,d] += sum_i c[b,i,j] * u_hat[b,i,j,d]
// u_hat recomputed on the fly from x (LDS, staged once) and W (L2-resident per XCD:
// isp == blockIdx&7 == XCD id -> each XCD streams only its 737 KB W slice from L2).
// ITER==1: c uniform = 0.1 (softmax of zeros), applied as premul at the end.
// ITER==2: logits = u_hat . v1,       v1 = squash(s1)   (squash fused in head)
// ITER==3: logits = u_hat . (v1+v2)   (linearity of the b-update in v)
//
// NOTE: no min-waves arg in __launch_bounds__ — rounds 1-2 showed that
// __launch_bounds__(640,5) makes hipcc cap VGPR at 48 and spill the hot loop
// to scratch (WRITE_SIZE 16-21 MB vs 1.5 MB legit). At the natural ~80 VGPR,
// 2 blocks/CU (5 waves/SIMD, cap 102) fit without any hint.
template<int ITER>
__global__ __launch_bounds__(NTHREADS)
void iter_kernel(const float* __restrict__ x, const float* __restrict__ Wt,
                 const float* __restrict__ s1, const float* __restrict__ s2,
                 float* __restrict__ s_out)
{
    const int g   = blockIdx.x >> 3;       // b-group 0..63
    const int isp = blockIdx.x & 7;        // i-split == XCD id (round-robin dispatch)
    const int b0  = g * BB;
    const int i_begin = isp * IRANGE;

    const int t = threadIdx.x;
    const int i_par = t / 40;              // 0..15
    const int r  = t - i_par * 40;
    const int j  = r >> 2;                 // 0..9
    const int dq = r & 3;                  // 0..3  (owns d = dq*4..dq*4+3)

    __shared__ float x_lds[BB][IRANGE][KDIM];   // 18.0 KB (whole slice, staged once)
    __shared__ float logit_lds[BB][CI][NJ];     // 2.5 KB
    __shared__ float c_lds[BB][CI][NJ];         // 2.5 KB
    __shared__ float s_lds[BB][JD];             // 2.5 KB

    // head: v for this thread's (j, dq) — fused squash of previous iteration(s)
    float4 vs[BB];
    if (ITER >= 2) {
        #pragma unroll
        for (int bb = 0; bb < BB; ++bb) {
            const float4 a = *(const float4*)(s1 + (size_t)(b0 + bb) * JD + j * ND + dq * 4);
            float q2 = dot4(a, a);
            q2 += __shfl_xor(q2, 1);           // sum over the 4-lane d-quad (16 d total)
            q2 += __shfl_xor(q2, 2);
            const float sc = q2 / (1.f + q2) / sqrtf(q2 + EPSQ);
            vs[bb] = make_float4(a.x * sc, a.y * sc, a.z * sc, a.w * sc);
            if (ITER == 3) {
                const float4 bv = *(const float4*)(s2 + (size_t)(b0 + bb) * JD + j * ND + dq * 4);
                float r2 = dot4(bv, bv);
                r2 += __shfl_xor(r2, 1);
                r2 += __shfl_xor(r2, 2);
                const float sc2 = r2 / (1.f + r2) / sqrtf(r2 + EPSQ);
                vs[bb].x += bv.x * sc2; vs[bb].y += bv.y * sc2;
                vs[bb].z += bv.z * sc2; vs[bb].w += bv.w * sc2;
            }
        }
    }

    // stage entire x slice: BB * 288 float4, contiguous & coalesced (2 rounds)
    {
        const int NF = (IRANGE * KDIM) / 4;    // 288 float4 per batch
        for (int idx = t; idx < BB * NF; idx += NTHREADS) {
            const int bb = idx / NF;
            const int f  = idx - bb * NF;
            ((float4*)&x_lds[bb][0][0])[f] =
                ((const float4*)(x + (size_t)(b0 + bb) * IN_CAPS * KDIM
                                   + (size_t)i_begin * KDIM))[f];
        }
    }
    __syncthreads();

    float4 s_acc[BB];
    #pragma unroll
    for (int bb = 0; bb < BB; ++bb) s_acc[bb] = make_float4(0.f, 0.f, 0.f, 0.f);

    const float* wp = Wt + (size_t)((i_begin + i_par) * NJ + j) * (KDIM * ND) + dq * 4;

    for (int c = 0; c < NCHUNK; ++c) {
        const int il = c * CI + i_par;

        // u_hat fragments in registers; W streamed float4-at-a-time (low live set)
        float4 u[BB];
        #pragma unroll
        for (int bb = 0; bb < BB; ++bb) u[bb] = make_float4(0.f, 0.f, 0.f, 0.f);
        #pragma unroll
        for (int h = 0; h < 2; ++h) {
            float xs[BB][4];
            #pragma unroll
            for (int bb = 0; bb < BB; ++bb) {
                const float4 xv = *(const float4*)&x_lds[bb][il][h * 4];  // ds_read_b128
                xs[bb][0] = xv.x; xs[bb][1] = xv.y; xs[bb][2] = xv.z; xs[bb][3] = xv.w;
            }
            #pragma unroll
            for (int kk = 0; kk < 4; ++kk) {
                const float4 w4 = *(const float4*)(wp + (h * 4 + kk) * ND);
                #pragma unroll
                for (int bb = 0; bb < BB; ++bb) {
                    const float xv = xs[bb][kk];
                    u[bb].x += xv * w4.x; u[bb].y += xv * w4.y;
                    u[bb].z += xv * w4.z; u[bb].w += xv * w4.w;
                }
            }
        }

        if (ITER == 1) {
            // uniform c: just accumulate. NO barriers at all in this loop.
            #pragma unroll
            for (int bb = 0; bb < BB; ++bb) {
                s_acc[bb].x += u[bb].x; s_acc[bb].y += u[bb].y;
                s_acc[bb].z += u[bb].z; s_acc[bb].w += u[bb].w;
            }
        } else {
            // logits -> LDS (one writer per (bb,i,j): the dq==0 lane)
            #pragma unroll
            for (int bb = 0; bb < BB; ++bb) {
                float v = dot4(u[bb], vs[bb]);
                v += __shfl_xor(v, 1);         // reduce over the 4-lane d-quad group
                v += __shfl_xor(v, 2);
                if (dq == 0) logit_lds[bb][i_par][j] = v;
            }
            __syncthreads();

            // cooperative softmax: exactly ONE entry per thread (640 == BB*CI*NJ)
            {
                const int bb  = t / (CI * NJ);
                const int rem = t - bb * (CI * NJ);
                const int il2 = rem / NJ;
                const int jj  = rem - il2 * NJ;
                float lv[NJ];
                float m = -1e30f;
                #pragma unroll
                for (int q = 0; q < NJ; ++q) {
                    lv[q] = logit_lds[bb][il2][q];
                    m = fmaxf(m, lv[q]);
                }
                float ssum = 0.f;
                #pragma unroll
                for (int q = 0; q < NJ; ++q) ssum += __expf(lv[q] - m);
                c_lds[bb][il2][jj] = __fdividef(__expf(lv[jj] - m), ssum);
            }
            __syncthreads();

            // s += c * u_hat (u_hat still in registers).
            // Safe w/o a 3rd barrier: next chunk touches logit_lds only, and the
            // next softmax read of logit_lds is again behind its own barrier.
            #pragma unroll
            for (int bb = 0; bb < BB; ++bb) {
                const float cc = c_lds[bb][i_par][j];
                s_acc[bb].x += cc * u[bb].x; s_acc[bb].y += cc * u[bb].y;
                s_acc[bb].z += cc * u[bb].z; s_acc[bb].w += cc * u[bb].w;
            }
        }

        wp += (size_t)CI * WSTRIDE;
    }

    // block-level reduction over i_par groups via LDS, then one global atomic each
    ((float*)s_lds)[t] = 0.f;   // NTHREADS == BB*JD
    __syncthreads();
    const float premul = (ITER == 1) ? 0.1f : 1.0f;   // softmax(zeros) over 10 caps
    #pragma unroll
    for (int bb = 0; bb < BB; ++bb) {
        atomicAdd(&s_lds[bb][j * ND + dq * 4 + 0], s_acc[bb].x * premul);
        atomicAdd(&s_lds[bb][j * ND + dq * 4 + 1], s_acc[bb].y * premul);
        atomicAdd(&s_lds[bb][j * ND + dq * 4 + 2], s_acc[bb].z * premul);
        atomicAdd(&s_lds[bb][j * ND + dq * 4 + 3], s_acc[bb].w * premul);
    }
    __syncthreads();
    {
        const int bb = t / JD;
        const int jd = t - bb * JD;
        unsafeAtomicAdd(&s_out[(size_t)(b0 + bb) * JD + jd], s_lds[bb][jd]);
    }
}

// final squash per (b,j): v = s * s2/(1+s2)/sqrt(s2+eps); 16-lane shuffle reduction.
__global__ __launch_bounds__(256)
void squash_kernel(const float* __restrict__ s, float* __restrict__ out)
{
    const int idx = blockIdx.x * 256 + threadIdx.x;   // grid 160 -> exactly 40960
    const float sv = s[idx];
    float sq = sv * sv;
    sq += __shfl_xor(sq, 1);
    sq += __shfl_xor(sq, 2);
    sq += __shfl_xor(sq, 4);
    sq += __shfl_xor(sq, 8);    // sum over the 16 d-lanes (16-aligned in wave)
    const float scale = sq / (1.0f + sq) / sqrtf(sq + EPSQ);
    out[idx] = sv * scale;
}

extern "C" void kernel_launch(void* const* d_in, const int* in_sizes, int n_in,
                              void* d_out, int out_size, void* d_ws, size_t ws_size,
                              hipStream_t stream)
{
    const float* x  = (const float*)d_in[0];   // [256,1152,8]
    const float* Wt = (const float*)d_in[1];   // [1152,10,8,16]
    float* out = (float*)d_out;                // [256,10,16]
    float* s1  = (float*)d_ws;                 // 40960 floats each
    float* s2  = s1 + (size_t)B_TOT * JD;
    float* s3  = s2 + (size_t)B_TOT * JD;

    // ws is re-poisoned before every launch: zero the three s accumulators (480 KB)
    hipMemsetAsync(d_ws, 0, 3 * (size_t)B_TOT * JD * sizeof(float), stream);

    dim3 grid((B_TOT / BB) * ISPLIT), blk(NTHREADS);

    iter_kernel<1><<<grid, blk, 0, stream>>>(x, Wt, nullptr, nullptr, s1);  // s1 = sum(0.1*u)
    iter_kernel<2><<<grid, blk, 0, stream>>>(x, Wt, s1, nullptr, s2);       // v1 in-head
    iter_kernel<3><<<grid, blk, 0, stream>>>(x, Wt, s1, s2, s3);            // v1+v2 in-head
    squash_kernel<<<dim3((B_TOT * JD) / 256), dim3(256), 0, stream>>>(s3, out);
}

// Round 4
// 201.047 us; speedup vs baseline: 1.4785x; 1.1826x over previous
//
#include <hip/hip_runtime.h>
#include <cstddef>

// Problem constants
#define B_TOT   256
#define IN_CAPS 1152
#define KDIM    8
#define NJ      10
#define ND      16
#define JD      160               // NJ*ND
#define WSTRIDE (NJ*KDIM*ND)      // 1280 floats per input capsule i

// Geometry: wave = 4 i × 16 d lanes; block = 4 independent waves (256 thr).
// ISPLIT=8 -> isp == blockIdx&7 == XCD id; W slice (144 i = 737 KB) L2-resident.
#define ISPLIT  8
#define IRANGE  (IN_CAPS/ISPLIT)  // 144
#define NSTEP   (IRANGE/16)       // 9 (4 waves * 4 i per step)
#define EPSQ    1e-7f

// One routing iteration, s_out[b,j,d] += sum_i c[b,i,j] * u_hat[b,i,j,d].
// Lane owns (i_sub, d): computes u[j] for all j; logit dot over d via 16-lane
// shfl_xor butterfly; softmax per-lane in registers. NO barriers in main loop —
// waves run fully decoupled (latency hiding via 80 independent W loads/step + TLP).
// ITER==1: c = 0.1 uniform (softmax of zeros), premultiplied at the end; BB=4.
// ITER==2: logits = u_hat . v1, v1 = squash(s1) computed in-head; BB=2.
// ITER==3: logits = u_hat . (v1+v2) (linearity of the b-update); BB=2.
template<int ITER>
__global__ __launch_bounds__(256)
void iter_kernel(const float* __restrict__ x, const float* __restrict__ Wt,
                 const float* __restrict__ s1, const float* __restrict__ s2,
                 float* __restrict__ s_out)
{
    constexpr int BBK = (ITER == 1) ? 4 : 2;

    const int g   = blockIdx.x >> 3;        // b-group
    const int isp = blockIdx.x & 7;         // XCD id (round-robin dispatch)
    const int b0  = g * BBK;
    const int i_begin = isp * IRANGE;

    const int t    = threadIdx.x;
    const int wv   = t >> 6;                // wave 0..3
    const int lane = t & 63;
    const int isub = (lane >> 4) & 3;       // which of the wave's 4 capsules
    const int d    = lane & 15;             // output dim owned by this lane

    __shared__ float red[4][BBK][NJ][ND];   // cross-wave reduction (5-10 KB)

    // head: v[bb][j] for this lane's d — fused squash of previous iteration(s)
    float v[BBK][NJ];
    if constexpr (ITER >= 2) {
        #pragma unroll
        for (int bb = 0; bb < BBK; ++bb) {
            #pragma unroll
            for (int j = 0; j < NJ; ++j) {
                const float a = s1[(size_t)(b0 + bb) * JD + j * ND + d];
                float q = a * a;
                q += __shfl_xor(q, 1); q += __shfl_xor(q, 2);
                q += __shfl_xor(q, 4); q += __shfl_xor(q, 8);   // sum over 16 d
                float vv = a * (q / (1.f + q) / sqrtf(q + EPSQ));
                if constexpr (ITER == 3) {
                    const float c2 = s2[(size_t)(b0 + bb) * JD + j * ND + d];
                    float r2 = c2 * c2;
                    r2 += __shfl_xor(r2, 1); r2 += __shfl_xor(r2, 2);
                    r2 += __shfl_xor(r2, 4); r2 += __shfl_xor(r2, 8);
                    vv += c2 * (r2 / (1.f + r2) / sqrtf(r2 + EPSQ));
                }
                v[bb][j] = vv;
            }
        }
    }

    float sacc[BBK][NJ];
    #pragma unroll
    for (int bb = 0; bb < BBK; ++bb)
        #pragma unroll
        for (int j = 0; j < NJ; ++j) sacc[bb][j] = 0.f;

    int i = i_begin + wv * 4 + isub;
    for (int step = 0; step < NSTEP; ++step, i += 16) {
        // x[b, i, 0..7] — 16 d-lanes share the address (coalesced to 32 B per i)
        float xs[BBK][KDIM];
        #pragma unroll
        for (int bb = 0; bb < BBK; ++bb) {
            const float* xb = x + (size_t)(b0 + bb) * IN_CAPS * KDIM + (size_t)i * KDIM;
            const float4 xa = *(const float4*)(xb);
            const float4 xc = *(const float4*)(xb + 4);
            xs[bb][0] = xa.x; xs[bb][1] = xa.y; xs[bb][2] = xa.z; xs[bb][3] = xa.w;
            xs[bb][4] = xc.x; xs[bb][5] = xc.y; xs[bb][6] = xc.z; xs[bb][7] = xc.w;
        }

        // u[bb][j] = sum_k x[bb,i,k] * W[i,j,k,d] — 80 independent scalar W loads
        // (16 d-lanes read 64 B contiguous, x4 i-groups per instruction)
        const float* wp = Wt + (size_t)i * WSTRIDE + d;
        float u[BBK][NJ];
        #pragma unroll
        for (int j = 0; j < NJ; ++j) {
            float wr[KDIM];
            #pragma unroll
            for (int k = 0; k < KDIM; ++k) wr[k] = wp[(j * KDIM + k) * ND];
            #pragma unroll
            for (int bb = 0; bb < BBK; ++bb) {
                float acc = 0.f;
                #pragma unroll
                for (int k = 0; k < KDIM; ++k) acc += xs[bb][k] * wr[k];
                u[bb][j] = acc;
            }
        }

        if constexpr (ITER == 1) {
            #pragma unroll
            for (int bb = 0; bb < BBK; ++bb)
                #pragma unroll
                for (int j = 0; j < NJ; ++j) sacc[bb][j] += u[bb][j];
        } else {
            #pragma unroll
            for (int bb = 0; bb < BBK; ++bb) {
                // logits: dot over full d via 16-lane butterfly (wave-local!)
                float lg[NJ];
                #pragma unroll
                for (int j = 0; j < NJ; ++j) {
                    float p = u[bb][j] * v[bb][j];
                    p += __shfl_xor(p, 1); p += __shfl_xor(p, 2);
                    p += __shfl_xor(p, 4); p += __shfl_xor(p, 8);
                    lg[j] = p;
                }
                // per-lane softmax over the 10 register-resident logits
                float m = lg[0];
                #pragma unroll
                for (int j = 1; j < NJ; ++j) m = fmaxf(m, lg[j]);
                float ssum = 0.f;
                #pragma unroll
                for (int j = 0; j < NJ; ++j) { lg[j] = __expf(lg[j] - m); ssum += lg[j]; }
                const float rinv = __fdividef(1.f, ssum);
                #pragma unroll
                for (int j = 0; j < NJ; ++j) sacc[bb][j] += (lg[j] * rinv) * u[bb][j];
            }
        }
    }

    // reduce the 4 i_subs inside the wave (lane bits 4,5), then cross-wave via LDS
    #pragma unroll
    for (int bb = 0; bb < BBK; ++bb)
        #pragma unroll
        for (int j = 0; j < NJ; ++j) {
            float p = sacc[bb][j];
            p += __shfl_xor(p, 16);
            p += __shfl_xor(p, 32);
            sacc[bb][j] = p;
        }
    if (lane < 16) {
        #pragma unroll
        for (int bb = 0; bb < BBK; ++bb)
            #pragma unroll
            for (int j = 0; j < NJ; ++j) red[wv][bb][j][d] = sacc[bb][j];
    }
    __syncthreads();   // the ONLY barrier in the kernel

    const float premul = (ITER == 1) ? 0.1f : 1.0f;   // softmax(zeros) over 10 caps
    for (int e = t; e < BBK * JD; e += 256) {
        const int bb  = e / JD;
        const int rem = e - bb * JD;                  // flattened [NJ][ND] index
        float tot = 0.f;
        #pragma unroll
        for (int w = 0; w < 4; ++w) tot += (&red[w][bb][0][0])[rem];
        unsafeAtomicAdd(&s_out[(size_t)(b0 + bb) * JD + rem], tot * premul);
    }
}

// final squash per (b,j): v = s * s2/(1+s2)/sqrt(s2+eps); 16-lane shuffle reduction.
__global__ __launch_bounds__(256)
void squash_kernel(const float* __restrict__ s, float* __restrict__ out)
{
    const int idx = blockIdx.x * 256 + threadIdx.x;   // grid 160 -> exactly 40960
    const float sv = s[idx];
    float sq = sv * sv;
    sq += __shfl_xor(sq, 1);
    sq += __shfl_xor(sq, 2);
    sq += __shfl_xor(sq, 4);
    sq += __shfl_xor(sq, 8);    // sum over the 16 d-lanes (16-aligned in wave)
    const float scale = sq / (1.0f + sq) / sqrtf(sq + EPSQ);
    out[idx] = sv * scale;
}

extern "C" void kernel_launch(void* const* d_in, const int* in_sizes, int n_in,
                              void* d_out, int out_size, void* d_ws, size_t ws_size,
                              hipStream_t stream)
{
    const float* x  = (const float*)d_in[0];   // [256,1152,8]
    const float* Wt = (const float*)d_in[1];   // [1152,10,8,16]
    float* out = (float*)d_out;                // [256,10,16]
    float* s1  = (float*)d_ws;                 // 40960 floats each
    float* s2  = s1 + (size_t)B_TOT * JD;
    float* s3  = s2 + (size_t)B_TOT * JD;

    // ws is re-poisoned before every launch: zero the three s accumulators (480 KB)
    hipMemsetAsync(d_ws, 0, 3 * (size_t)B_TOT * JD * sizeof(float), stream);

    dim3 g1((B_TOT / 4) * ISPLIT);    // 512 blocks  (ITER1, BB=4)
    dim3 g23((B_TOT / 2) * ISPLIT);   // 1024 blocks (ITER2/3, BB=2)
    dim3 blk(256);

    iter_kernel<1><<<g1,  blk, 0, stream>>>(x, Wt, nullptr, nullptr, s1);
    iter_kernel<2><<<g23, blk, 0, stream>>>(x, Wt, s1, nullptr, s2);
    iter_kernel<3><<<g23, blk, 0, stream>>>(x, Wt, s1, s2, s3);
    squash_kernel<<<dim3((B_TOT * JD) / 256), blk, 0, stream>>>(s3, out);
}